// Round 12
// baseline (162.094 us; speedup 1.0000x reference)
//
#include <hip/hip_runtime.h>
#include <hip/hip_fp16.h>

#define NN 100000
#define EE 640000
#define D 128
#define NBINS NN
#define SCAN_NBLK 98          // ceil(100000/1024)  (mid tier)

#define BKT 1563              // ceil(100000/64) coarse buckets (64 nodes each)
#define EBLK 256              // edge-chunk blocks
#define EPB 2500              // edges per chunk block (256*2500 = 640000)

// ---------------------------------------------------------------------------
// TOP-tier workspace layout (4-byte units) — atomic-free sort, fused agg+GEMM:
//   lcnt  [0       , 400128)    per-(block,bucket) counts -> excl. prefixes
//   tot   [400128  , 401691)    per-bucket totals
//   boffs [401728  , 403293)    bucket offsets (exclusive) + boffs[BKT]=E
//   offs  [403328  , 503329)    node-exact CSR offsets + offs[NN]=E
//   sw    [503360  , 1783360)   bucket-grouped (src|dstlow, w) int2
//   sw2   [1783360 , 3063360)   node-sorted (src, w) int2
//   Wf    [3063360 , 3079744)   W as f16 [128 c][256 k]
//   xh    [3079744 , 9479744)   x as f16 [100000][128]
// ---------------------------------------------------------------------------
#define WS_LCNT     0
#define WS_TOT      400128
#define WS_BOFFS    401728
#define WS_OFFS     403328
#define WS_SW       503360
#define WS_SW2      1783360
#define WS_WF       3063360
#define WS_XH       3079744
#define WS_INTS_TOP 9479744

// MID-tier (R4 fp32 path) layout
#define WS_CNTM     0
#define WS_OFFSM    100000
#define WS_BSUMM    200000
#define WS_SWM      200192
#define WS_WCONV    1480192
#define WS_INTS_MID 1512960

// prepA block partition
#define PREP_XB 3125          // x->f16 : 3125*256*16 = 12.8M elems
#define PREP_WB 128           // W->f16 : 128*256    = 32768 elems
#define PREP_AB EBLK          // passA  : 256 blocks * 2500 edges

typedef __attribute__((ext_vector_type(8))) short    short8v;
typedef __attribute__((ext_vector_type(8))) _Float16 half8v;
typedef __attribute__((ext_vector_type(4))) float    floatx4;
struct __align__(8) half4t { __half2 a, b; };

__device__ inline void split_bf16(float f, short& h, short& l) {
    unsigned u  = __float_as_uint(f);
    unsigned hb = u & 0xFFFF0000u;
    h = (short)(u >> 16);
    float fl = f - __uint_as_float(hb);
    l = (short)(__float_as_uint(fl) >> 16);
}

// ---- fallback path (atomic scatter), used only if ws tiny ------------------
__global__ __launch_bounds__(256) void scatter_kernel(
    const float* __restrict__ x, const int* __restrict__ ei,
    const float* __restrict__ ew, float* agg)
{
    int gid = blockIdx.x * 256 + threadIdx.x;
    int e = gid >> 7, f = gid & 127;
    if (e >= EE) return;
    float v = x[ei[e] * D + f] * ew[e];
    unsafeAtomicAdd(&agg[ei[EE + e] * D + f], v);
}

// ---- prepA: x->f16 | W->f16 | per-block LDS bucket histogram ---------------
__global__ __launch_bounds__(256) void prepA_kernel(
    const float* __restrict__ x, const float* __restrict__ Wrel,
    const float* __restrict__ Wroot, const int* __restrict__ ei,
    short* __restrict__ xh, short* __restrict__ Wf, int* __restrict__ lcnt)
{
    __shared__ int h[BKT];
    const int b = blockIdx.x;
    if (b < PREP_XB) {
        const int base = b * 4096 + threadIdx.x * 4;   // f32 index
        float4 v[4];
        #pragma unroll
        for (int u = 0; u < 4; u++)
            v[u] = *(const float4*)&x[base + u * 1024];
        #pragma unroll
        for (int u = 0; u < 4; u++) {
            short4 hh;
            hh.x = (short)__half_as_ushort(__float2half(v[u].x));
            hh.y = (short)__half_as_ushort(__float2half(v[u].y));
            hh.z = (short)__half_as_ushort(__float2half(v[u].z));
            hh.w = (short)__half_as_ushort(__float2half(v[u].w));
            *(short4*)&xh[base + u * 1024] = hh;
        }
    } else if (b < PREP_XB + PREP_WB) {
        int i = (b - PREP_XB) * 256 + threadIdx.x;   // 0..32767
        int c = i >> 8, k = i & 255;
        float f = (k < 128) ? Wrel[c * 128 + k] : Wroot[c * 128 + (k - 128)];
        Wf[i] = (short)__half_as_ushort(__float2half(f));
    } else {
        const int eb = b - PREP_XB - PREP_WB;        // 0..255
        for (int i = threadIdx.x; i < BKT; i += 256) h[i] = 0;
        __syncthreads();
        const int e0 = eb * EPB, e1 = e0 + EPB;
        for (int e = e0 + threadIdx.x; e < e1; e += 256)
            atomicAdd(&h[ei[EE + e] >> 6], 1);       // LDS atomic (cheap)
        __syncthreads();
        for (int i = threadIdx.x; i < BKT; i += 256)
            lcnt[eb * BKT + i] = h[i];
    }
}

// ---- colscan: per-bucket exclusive scan over 256 block rows (in place) -----
__global__ __launch_bounds__(256) void colscan_kernel(
    int* __restrict__ lcnt, int* __restrict__ tot)
{
    int t = blockIdx.x * 256 + threadIdx.x;
    if (t >= BKT) return;
    int run = 0;
    for (int b = 0; b < EBLK; b++) {
        int v = lcnt[b * BKT + t];
        lcnt[b * BKT + t] = run;     // exclusive prefix
        run += v;
    }
    tot[t] = run;
}

// ---- scanT: exclusive scan of bucket totals -> boffs -----------------------
__global__ __launch_bounds__(256) void scanT_kernel(
    const int* __restrict__ tot, int* __restrict__ boffs)
{
    __shared__ int s[256];
    __shared__ int carry;
    if (threadIdx.x == 0) carry = 0;
    __syncthreads();
    for (int c = 0; c < 7; c++) {                    // 7*256 = 1792 >= 1563
        int idx = c * 256 + threadIdx.x;
        int v = (idx < BKT) ? tot[idx] : 0;
        s[threadIdx.x] = v;
        __syncthreads();
        for (int off = 1; off < 256; off <<= 1) {
            int t = (threadIdx.x >= off) ? s[threadIdx.x - off] : 0;
            __syncthreads();
            s[threadIdx.x] += t;
            __syncthreads();
        }
        if (idx < BKT) boffs[idx] = carry + s[threadIdx.x] - v;
        __syncthreads();
        if (threadIdx.x == 0) carry += s[255];
        __syncthreads();
    }
    if (threadIdx.x == 0) boffs[BKT] = EE;
}

// ---- passB: bucket-grouped scatter (no global atomics) ---------------------
__global__ __launch_bounds__(256) void passB_kernel(
    const int* __restrict__ ei, const float* __restrict__ ew,
    const int* __restrict__ lcnt, const int* __restrict__ boffs,
    int2* __restrict__ sw)
{
    __shared__ int base2[BKT];
    __shared__ int cur[BKT];
    const int eb = blockIdx.x;
    for (int i = threadIdx.x; i < BKT; i += 256) {
        base2[i] = boffs[i] + lcnt[eb * BKT + i];
        cur[i] = 0;
    }
    __syncthreads();
    const int e0 = eb * EPB, e1 = e0 + EPB;
    for (int e = e0 + threadIdx.x; e < e1; e += 256) {
        int src = ei[e];
        int dst = ei[EE + e];
        int bkt = dst >> 6;
        int r = atomicAdd(&cur[bkt], 1);             // LDS rank
        sw[base2[bkt] + r] = make_int2(src | ((dst & 63) << 17),
                                       __float_as_int(ew[e]));
    }
}

// ---- passC: node-exact refine within each bucket + CSR offsets -------------
__global__ __launch_bounds__(256) void passC_kernel(
    const int2* __restrict__ sw, const int* __restrict__ boffs,
    int2* __restrict__ sw2, int* __restrict__ offs)
{
    __shared__ int cnt[64], nb[64], cur[64];
    __shared__ int segbeg, segend;
    const int bkt = blockIdx.x;
    if (threadIdx.x == 0) { segbeg = boffs[bkt]; segend = boffs[bkt + 1]; }
    if (threadIdx.x < 64) { cnt[threadIdx.x] = 0; cur[threadIdx.x] = 0; }
    __syncthreads();
    for (int j = segbeg + threadIdx.x; j < segend; j += 256)
        atomicAdd(&cnt[(sw[j].x >> 17) & 63], 1);
    __syncthreads();
    if (threadIdx.x < 64) nb[threadIdx.x] = cnt[threadIdx.x];
    __syncthreads();
    for (int off = 1; off < 64; off <<= 1) {
        int t = 0;
        if (threadIdx.x < 64 && threadIdx.x >= off) t = nb[threadIdx.x - off];
        __syncthreads();
        if (threadIdx.x < 64) nb[threadIdx.x] += t;
        __syncthreads();
    }
    if (threadIdx.x < 64) {
        int b = segbeg + nb[threadIdx.x] - cnt[threadIdx.x];   // exclusive base
        nb[threadIdx.x] = b;
        int node = bkt * 64 + threadIdx.x;
        if (node < NN) offs[node] = b;
    }
    __syncthreads();
    for (int j = segbeg + threadIdx.x; j < segend; j += 256) {
        int2 v = sw[j];
        int n = (v.x >> 17) & 63;
        int r = atomicAdd(&cur[n], 1);
        sw2[nb[n] + r] = make_int2(v.x & 0x1FFFF, v.y);
    }
    if (bkt == 0 && threadIdx.x == 0) offs[NN] = EE;
}

// ---- fused aggregate + f16 MFMA GEMM ---------------------------------------
// Phase 1: each block aggregates its own 128 rows (half-wave per node, fp16
//          gather 4-deep) directly into the swizzled LDS tile aggT (f16).
// Phase 2: out = [agg|xh] @ Wf^T + b, with kc 0/1 A-fragments read from aggT.
// LDS 64 KB -> 2 blocks/CU. Numerics identical to the split version.
__global__ __launch_bounds__(256) void fused_agg_gemm_kernel(
    const short* __restrict__ xh, const int* __restrict__ offs,
    const int2* __restrict__ sw2, const short* __restrict__ Wf,
    const float* __restrict__ bias, float* __restrict__ out)
{
    __shared__ short aggT[16384];  // 2 chunks x [128][64]-swizzled, 32 KB
    __shared__ short At[8192];     // xh staging chunk, 16 KB
    __shared__ short Wt[8192];     // W chunk, 16 KB

    const int tid  = threadIdx.x;
    const int lane = tid & 63;
    const int wave = tid >> 6;
    const int row0 = blockIdx.x * 128;
    const int frow = lane & 15;

    // ---------------- phase 1: aggregate own 128 rows into aggT -------------
    {
        const int hw = tid >> 5;                 // half-wave 0..7
        const int fl = tid & 31;
        const int ac = fl >> 4;                  // chunk 0/1
        const int klocal = (fl * 4) & 63;
        const half4t* xp = (const half4t*)xh;
        for (int t = 0; t < 16; t++) {
            const int r = hw * 16 + t;
            const int node = row0 + r;
            float4 a0 = make_float4(0.f, 0.f, 0.f, 0.f);
            float4 a1 = make_float4(0.f, 0.f, 0.f, 0.f);
            if (node < NN) {
                const int beg = offs[node], end = offs[node + 1];
                int j = beg;
                for (; j + 3 < end; j += 4) {
                    int2 s0 = sw2[j], s1 = sw2[j + 1], s2 = sw2[j + 2], s3 = sw2[j + 3];
                    half4t v0 = xp[(size_t)s0.x * 32 + fl];
                    half4t v1 = xp[(size_t)s1.x * 32 + fl];
                    half4t v2 = xp[(size_t)s2.x * 32 + fl];
                    half4t v3 = xp[(size_t)s3.x * 32 + fl];
                    float w0 = __int_as_float(s0.y), w1 = __int_as_float(s1.y);
                    float w2 = __int_as_float(s2.y), w3 = __int_as_float(s3.y);
                    float2 l0 = __half22float2(v0.a), h0 = __half22float2(v0.b);
                    float2 l1 = __half22float2(v1.a), h1 = __half22float2(v1.b);
                    float2 l2 = __half22float2(v2.a), h2 = __half22float2(v2.b);
                    float2 l3 = __half22float2(v3.a), h3 = __half22float2(v3.b);
                    a0.x += w0 * l0.x; a0.y += w0 * l0.y; a0.z += w0 * h0.x; a0.w += w0 * h0.y;
                    a1.x += w1 * l1.x; a1.y += w1 * l1.y; a1.z += w1 * h1.x; a1.w += w1 * h1.y;
                    a0.x += w2 * l2.x; a0.y += w2 * l2.y; a0.z += w2 * h2.x; a0.w += w2 * h2.y;
                    a1.x += w3 * l3.x; a1.y += w3 * l3.y; a1.z += w3 * h3.x; a1.w += w3 * h3.y;
                }
                for (; j + 1 < end; j += 2) {
                    int2 s0 = sw2[j], s1 = sw2[j + 1];
                    half4t v0 = xp[(size_t)s0.x * 32 + fl];
                    half4t v1 = xp[(size_t)s1.x * 32 + fl];
                    float w0 = __int_as_float(s0.y), w1 = __int_as_float(s1.y);
                    float2 l0 = __half22float2(v0.a), h0 = __half22float2(v0.b);
                    float2 l1 = __half22float2(v1.a), h1 = __half22float2(v1.b);
                    a0.x += w0 * l0.x; a0.y += w0 * l0.y; a0.z += w0 * h0.x; a0.w += w0 * h0.y;
                    a1.x += w1 * l1.x; a1.y += w1 * l1.y; a1.z += w1 * h1.x; a1.w += w1 * h1.y;
                }
                if (j < end) {
                    int2 s0 = sw2[j];
                    half4t v0 = xp[(size_t)s0.x * 32 + fl];
                    float w0 = __int_as_float(s0.y);
                    float2 l0 = __half22float2(v0.a), h0 = __half22float2(v0.b);
                    a0.x += w0 * l0.x; a0.y += w0 * l0.y; a0.z += w0 * h0.x; a0.w += w0 * h0.y;
                }
            }
            half4t o;
            o.a = __floats2half2_rn(a0.x + a1.x, a0.y + a1.y);
            o.b = __floats2half2_rn(a0.z + a1.z, a0.w + a1.w);
            int sidx = ac * 8192 + r * 64 + (((klocal >> 3) ^ (r & 7)) << 3) + (klocal & 7);
            *(half4t*)&aggT[sidx] = o;
        }
    }

    // ---------------- phase 2: GEMM ------------------------------------------
    floatx4 acc[2][8];
    #pragma unroll
    for (int nf = 0; nf < 8; nf++) {
        float b = bias[nf * 16 + frow];
        #pragma unroll
        for (int mf = 0; mf < 2; mf++) acc[mf][nf] = (floatx4){b, b, b, b};
    }

    for (int kc = 0; kc < 4; kc++) {
        __syncthreads();   // phase-1 done / previous iter's reads done
        if (kc >= 2) {
            #pragma unroll
            for (int i = 0; i < 4; i++) {
                int e = (i * 256 + tid) * 8;
                int r = e >> 6, k = e & 63;
                int rg = row0 + r;
                short8v v = (short8v)0;
                if (rg < NN)
                    v = *(const short8v*)&xh[(size_t)rg * 128 + (kc - 2) * 64 + k];
                int sidx = r * 64 + (((k >> 3) ^ (r & 7)) << 3);
                *(short8v*)&At[sidx] = v;
            }
        }
        #pragma unroll
        for (int i = 0; i < 4; i++) {
            int e = (i * 256 + tid) * 8;
            int c = e >> 6, k = e & 63;
            int sidx = c * 64 + (((k >> 3) ^ (c & 7)) << 3);
            *(short8v*)&Wt[sidx] = *(const short8v*)&Wf[c * 256 + kc * 64 + k];
        }
        __syncthreads();

        const short* Asrc = (kc < 2) ? &aggT[kc * 8192] : At;
        const int arow = wave * 32;
        #pragma unroll
        for (int kf = 0; kf < 2; kf++) {
            const int kblk = kf * 4 + (lane >> 4);
            half8v a[2];
            #pragma unroll
            for (int mf = 0; mf < 2; mf++) {
                int r = arow + mf * 16 + frow;
                int idx = r * 64 + ((kblk ^ (r & 7)) << 3);
                a[mf] = *(const half8v*)&Asrc[idx];
            }
            #pragma unroll
            for (int nf = 0; nf < 8; nf++) {
                int cc = nf * 16 + frow;
                int idx = cc * 64 + ((kblk ^ (cc & 7)) << 3);
                half8v b = *(const half8v*)&Wt[idx];
                #pragma unroll
                for (int mf = 0; mf < 2; mf++)
                    acc[mf][nf] = __builtin_amdgcn_mfma_f32_16x16x32_f16(a[mf], b, acc[mf][nf], 0, 0, 0);
            }
        }
    }

    const int orow = row0 + wave * 32;
    #pragma unroll
    for (int mf = 0; mf < 2; mf++) {
        #pragma unroll
        for (int j = 0; j < 4; j++) {
            int r = orow + mf * 16 + (lane >> 4) * 4 + j;
            if (r < NN) {
                #pragma unroll
                for (int nf = 0; nf < 8; nf++)
                    out[(size_t)r * D + nf * 16 + (lane & 15)] = acc[mf][nf][j];
            }
        }
    }
}

// ======================= MID-tier kernels (R4 fp32 path) =====================
__global__ __launch_bounds__(256) void zero_cnt_kernel(int* __restrict__ cnt)
{
    int i = blockIdx.x * 256 + threadIdx.x;
    if (i < NBINS) cnt[i] = 0;
}

__global__ __launch_bounds__(256) void hist_kernel(
    const int* __restrict__ ei, int* __restrict__ cnt)
{
    int e = blockIdx.x * 256 + threadIdx.x;
    if (e < EE) atomicAdd(&cnt[ei[EE + e]], 1);
}

__global__ __launch_bounds__(256) void wconv_kernel(
    const float* __restrict__ Wrel, const float* __restrict__ Wroot,
    short* __restrict__ Wb)
{
    int i = blockIdx.x * 256 + threadIdx.x;
    int c = i >> 8, k = i & 255;
    float f = (k < 128) ? Wrel[c * 128 + k] : Wroot[c * 128 + (k - 128)];
    short h, l;
    split_bf16(f, h, l);
    Wb[i] = h;
    Wb[32768 + i] = l;
}

__global__ __launch_bounds__(256) void scanA_kernel(
    const int* __restrict__ cnt, int* __restrict__ offs, int* __restrict__ bsum)
{
    __shared__ int tsum[256];
    const int tid = threadIdx.x;
    const int base = blockIdx.x * 1024 + tid * 4;
    int v[4], s = 0;
    #pragma unroll
    for (int i = 0; i < 4; i++) {
        int idx = base + i;
        v[i] = (idx < NBINS) ? cnt[idx] : 0;
        s += v[i];
    }
    tsum[tid] = s;
    __syncthreads();
    for (int off = 1; off < 256; off <<= 1) {
        int t = (tid >= off) ? tsum[tid - off] : 0;
        __syncthreads();
        tsum[tid] += t;
        __syncthreads();
    }
    int run = tsum[tid] - s;
    #pragma unroll
    for (int i = 0; i < 4; i++) {
        int idx = base + i;
        if (idx < NBINS) offs[idx] = run;
        run += v[i];
    }
    if (tid == 255) bsum[blockIdx.x] = tsum[255];
}

__global__ __launch_bounds__(256) void scanC_kernel(
    int* __restrict__ offs, const int* __restrict__ bsum)
{
    __shared__ int s[128];
    const int tid = threadIdx.x;
    if (tid < 128) s[tid] = (tid < SCAN_NBLK) ? bsum[tid] : 0;
    __syncthreads();
    for (int off = 1; off < 128; off <<= 1) {
        int t = 0;
        if (tid < 128 && tid >= off) t = s[tid - off];
        __syncthreads();
        if (tid < 128) s[tid] += t;
        __syncthreads();
    }
    const int add = (blockIdx.x == 0) ? 0 : s[blockIdx.x - 1];
    const int base = blockIdx.x * 1024 + tid * 4;
    #pragma unroll
    for (int i = 0; i < 4; i++) {
        int idx = base + i;
        if (idx < NBINS) offs[idx] += add;
    }
}

__global__ __launch_bounds__(256) void buildM_kernel(
    const int* __restrict__ ei, const float* __restrict__ ew,
    int* __restrict__ offs, int2* __restrict__ sw)
{
    int e = blockIdx.x * 256 + threadIdx.x;
    if (e >= EE) return;
    int dst = ei[EE + e];
    int p = atomicAdd(&offs[dst], 1);
    sw[p] = make_int2(ei[e], __float_as_int(ew[e]));
}

__global__ __launch_bounds__(256) void aggregate_kernel(
    const float* __restrict__ x, const int* __restrict__ offs,
    const int2* __restrict__ sw, float* __restrict__ out)
{
    const int node = blockIdx.x * 8 + (threadIdx.x >> 5);
    const int fl   = threadIdx.x & 31;
    if (node >= NN) return;
    const int beg = (node == 0) ? 0 : offs[node - 1];
    const int end = offs[node];
    const float4* x4 = (const float4*)x;

    float4 a0 = make_float4(0.f, 0.f, 0.f, 0.f);
    float4 a1 = make_float4(0.f, 0.f, 0.f, 0.f);
    int j = beg;
    for (; j + 1 < end; j += 2) {
        int2 s0 = sw[j];
        int2 s1 = sw[j + 1];
        float4 v0 = x4[(size_t)s0.x * 32 + fl];
        float4 v1 = x4[(size_t)s1.x * 32 + fl];
        float w0 = __int_as_float(s0.y), w1 = __int_as_float(s1.y);
        a0.x += w0 * v0.x; a0.y += w0 * v0.y; a0.z += w0 * v0.z; a0.w += w0 * v0.w;
        a1.x += w1 * v1.x; a1.y += w1 * v1.y; a1.z += w1 * v1.z; a1.w += w1 * v1.w;
    }
    if (j < end) {
        int2 s0 = sw[j];
        float4 v0 = x4[(size_t)s0.x * 32 + fl];
        float w0 = __int_as_float(s0.y);
        a0.x += w0 * v0.x; a0.y += w0 * v0.y; a0.z += w0 * v0.z; a0.w += w0 * v0.w;
    }
    float4 r = make_float4(a0.x + a1.x, a0.y + a1.y, a0.z + a1.z, a0.w + a1.w);
    ((float4*)out)[(size_t)node * 32 + fl] = r;
}

__global__ __launch_bounds__(256) void mfma_gemm_kernel(
    const float* __restrict__ x, const short* __restrict__ Wb,
    const float* __restrict__ bias, float* __restrict__ out)
{
    __shared__ short lds[4 * 128 * 64];
    short* Ah = lds;
    short* Al = lds + 8192;
    short* Wh = lds + 16384;
    short* Wl = lds + 24576;

    const int tid  = threadIdx.x;
    const int lane = tid & 63;
    const int wave = tid >> 6;
    const int row0 = blockIdx.x * 128;
    const int frow = lane & 15;
    const int fk   = (lane >> 4) * 8;

    floatx4 acc[2][8];
    #pragma unroll
    for (int nf = 0; nf < 8; nf++) {
        float b = bias[nf * 16 + frow];
        #pragma unroll
        for (int mf = 0; mf < 2; mf++) acc[mf][nf] = (floatx4){b, b, b, b};
    }

    for (int kc = 0; kc < 4; kc++) {
        const float* A = (kc < 2) ? out : x;
        const int kcol = (kc & 1) * 64;
        __syncthreads();
        #pragma unroll
        for (int i = 0; i < 8; i++) {
            int e = (i * 256 + tid) * 4;
            int r = e >> 6, k = e & 63;
            int rg = row0 + r;
            float4 v = (rg < NN) ? *(const float4*)&A[(size_t)rg * D + kcol + k]
                                 : make_float4(0.f, 0.f, 0.f, 0.f);
            short4 h, l;
            split_bf16(v.x, h.x, l.x);
            split_bf16(v.y, h.y, l.y);
            split_bf16(v.z, h.z, l.z);
            split_bf16(v.w, h.w, l.w);
            int sidx = r * 64 + (((k >> 3) ^ (r & 7)) << 3) + (k & 7);
            *(short4*)&Ah[sidx] = h;
            *(short4*)&Al[sidx] = l;
        }
        #pragma unroll
        for (int i = 0; i < 4; i++) {
            int e = (i * 256 + tid) * 8;
            int c = e >> 6, k = e & 63;
            int sidx = c * 64 + (((k >> 3) ^ (c & 7)) << 3);
            int g = c * 256 + kc * 64 + k;
            *(short8v*)&Wh[sidx] = *(const short8v*)&Wb[g];
            *(short8v*)&Wl[sidx] = *(const short8v*)&Wb[32768 + g];
        }
        __syncthreads();

        const int arow = wave * 32;
        #pragma unroll
        for (int kf = 0; kf < 2; kf++) {
            const int kblk = (kf * 32 + fk) >> 3;
            short8v ah[2], al[2];
            #pragma unroll
            for (int mf = 0; mf < 2; mf++) {
                int r = arow + mf * 16 + frow;
                int idx = r * 64 + ((kblk ^ (r & 7)) << 3);
                ah[mf] = *(const short8v*)&Ah[idx];
                al[mf] = *(const short8v*)&Al[idx];
            }
            #pragma unroll
            for (int nf = 0; nf < 8; nf++) {
                int cc = nf * 16 + frow;
                int idx = cc * 64 + ((kblk ^ (cc & 7)) << 3);
                short8v bh = *(const short8v*)&Wh[idx];
                short8v bl = *(const short8v*)&Wl[idx];
                #pragma unroll
                for (int mf = 0; mf < 2; mf++) {
                    acc[mf][nf] = __builtin_amdgcn_mfma_f32_16x16x32_bf16(ah[mf], bh, acc[mf][nf], 0, 0, 0);
                    acc[mf][nf] = __builtin_amdgcn_mfma_f32_16x16x32_bf16(al[mf], bh, acc[mf][nf], 0, 0, 0);
                    acc[mf][nf] = __builtin_amdgcn_mfma_f32_16x16x32_bf16(ah[mf], bl, acc[mf][nf], 0, 0, 0);
                }
            }
        }
    }

    const int orow = row0 + wave * 32;
    #pragma unroll
    for (int mf = 0; mf < 2; mf++) {
        #pragma unroll
        for (int j = 0; j < 4; j++) {
            int r = orow + mf * 16 + (lane >> 4) * 4 + j;
            if (r < NN) {
                #pragma unroll
                for (int nf = 0; nf < 8; nf++)
                    out[(size_t)r * D + nf * 16 + (lane & 15)] = acc[mf][nf][j];
            }
        }
    }
}

// ---- fallback fp32 GEMM (atomic tier only) ---------------------------------
__global__ __launch_bounds__(512) void gemm_kernel(
    const float* __restrict__ x, const float* __restrict__ Wrel,
    const float* __restrict__ Wroot, const float* __restrict__ bias,
    float* out)
{
    __shared__ float AtT[128][65];
    const int tid  = threadIdx.x;
    const int lane = tid & 63;
    const int wid  = __builtin_amdgcn_readfirstlane(tid >> 6);
    const int row0 = blockIdx.x * 64;
    float acc[16];
    {
        const float* bb = bias + wid * 16;
        #pragma unroll
        for (int c = 0; c < 16; c++) acc[c] = bb[c];
    }
    for (int phase = 0; phase < 2; phase++) {
        const float* A = phase ? x : out;
        const float* W = (phase ? Wroot : Wrel) + wid * 16 * D;
        __syncthreads();
        #pragma unroll
        for (int i = 0; i < 16; i++) {
            int e = i * 512 + tid;
            int r = e >> 7, k = e & 127;
            int rg = row0 + r;
            AtT[k][r] = (rg < NN) ? A[rg * D + k] : 0.0f;
        }
        __syncthreads();
        for (int k4 = 0; k4 < 32; k4++) {
            float a0 = AtT[k4 * 4 + 0][lane];
            float a1 = AtT[k4 * 4 + 1][lane];
            float a2 = AtT[k4 * 4 + 2][lane];
            float a3 = AtT[k4 * 4 + 3][lane];
            #pragma unroll
            for (int c = 0; c < 16; c++) {
                const float* wp = W + c * D + k4 * 4;
                acc[c] += a0 * wp[0] + a1 * wp[1] + a2 * wp[2] + a3 * wp[3];
            }
        }
    }
    __syncthreads();
    #pragma unroll
    for (int c = 0; c < 16; c++)
        AtT[wid * 16 + c][lane] = acc[c];
    __syncthreads();
    #pragma unroll
    for (int i = 0; i < 16; i++) {
        int e = i * 512 + tid;
        int r = e >> 7, col = e & 127;
        int rg = row0 + r;
        if (rg < NN) out[rg * D + col] = AtT[col][r];
    }
}

extern "C" void kernel_launch(void* const* d_in, const int* in_sizes, int n_in,
                              void* d_out, int out_size, void* d_ws, size_t ws_size,
                              hipStream_t stream) {
    const float* x     = (const float*)d_in[0];
    const int*   ei    = (const int*)  d_in[1];
    const float* ew    = (const float*)d_in[2];
    const float* Wrel  = (const float*)d_in[3];
    const float* Wroot = (const float*)d_in[4];
    const float* bias  = (const float*)d_in[5];
    float*       out   = (float*)d_out;

    const int eb = (EE + 255) / 256;

    if (ws_size >= (size_t)WS_INTS_TOP * sizeof(int)) {
        int* w = (int*)d_ws;
        int*   lcnt  = w + WS_LCNT;
        int*   tot   = w + WS_TOT;
        int*   boffs = w + WS_BOFFS;
        int*   offs  = w + WS_OFFS;
        int2*  sw    = (int2*)(w + WS_SW);
        int2*  sw2   = (int2*)(w + WS_SW2);
        short* Wf    = (short*)(w + WS_WF);
        short* xh    = (short*)(w + WS_XH);

        prepA_kernel<<<PREP_XB + PREP_WB + PREP_AB, 256, 0, stream>>>(
            x, Wrel, Wroot, ei, xh, Wf, lcnt);
        colscan_kernel<<<(BKT + 255) / 256, 256, 0, stream>>>(lcnt, tot);
        scanT_kernel<<<1, 256, 0, stream>>>(tot, boffs);
        passB_kernel<<<EBLK, 256, 0, stream>>>(ei, ew, lcnt, boffs, sw);
        passC_kernel<<<BKT, 256, 0, stream>>>(sw, boffs, sw2, offs);
        fused_agg_gemm_kernel<<<(NN + 127) / 128, 256, 0, stream>>>(
            xh, offs, sw2, Wf, bias, out);
    } else if (ws_size >= (size_t)WS_INTS_MID * sizeof(int)) {
        int* w = (int*)d_ws;
        int*   cnt  = w + WS_CNTM;
        int*   offs = w + WS_OFFSM;
        int*   bsum = w + WS_BSUMM;
        int2*  sw   = (int2*)(w + WS_SWM);
        short* Wb   = (short*)(w + WS_WCONV);

        zero_cnt_kernel<<<(NBINS + 255) / 256, 256, 0, stream>>>(cnt);
        wconv_kernel<<<128, 256, 0, stream>>>(Wrel, Wroot, Wb);
        hist_kernel <<<eb, 256, 0, stream>>>(ei, cnt);
        scanA_kernel<<<SCAN_NBLK, 256, 0, stream>>>(cnt, offs, bsum);
        scanC_kernel<<<SCAN_NBLK, 256, 0, stream>>>(offs, bsum);
        buildM_kernel<<<eb, 256, 0, stream>>>(ei, ew, offs, sw);
        aggregate_kernel<<<NN / 8, 256, 0, stream>>>(x, offs, sw, out);
        mfma_gemm_kernel<<<(NN + 127) / 128, 256, 0, stream>>>(x, Wb, bias, out);
    } else {
        hipMemsetAsync(out, 0, (size_t)NN * D * sizeof(float), stream);
        scatter_kernel<<<(EE * 128) / 256, 256, 0, stream>>>(x, ei, ew, out);
        gemm_kernel<<<(NN + 63) / 64, 512, 0, stream>>>(x, Wrel, Wroot, bias, out);
    }
}

// Round 13
// 116.588 us; speedup vs baseline: 1.3903x; 1.3903x over previous
//
#include <hip/hip_runtime.h>
#include <hip/hip_fp16.h>

#define NN 100000
#define EE 640000
#define D 128
#define NBINS NN
#define SCAN_NBLK 98          // ceil(100000/1024)  (mid tier)

#define BKT 1563              // ceil(100000/64) coarse buckets (64 nodes each)
#define EBLK 256              // edge-chunk blocks
#define EPB 2500              // edges per chunk block (256*2500 = 640000)

// ---------------------------------------------------------------------------
// TOP-tier workspace layout (4-byte units) — atomic-free sort:
//   lcnt  [0       , 400128)    per-(block,bucket) counts -> excl. prefixes
//   tot   [400128  , 401691)    per-bucket totals
//   boffs [401728  , 403293)    bucket offsets (exclusive) + boffs[BKT]=E
//   offs  [403328  , 503329)    node-exact CSR offsets + offs[NN]=E
//   sw    [503360  , 1783360)   bucket-grouped (src|dstlow, w) int2
//   sw2   [1783360 , 3063360)   node-sorted (src, w) int2
//   Wf    [3063360 , 3079744)   W as f16 [128 c][256 k]
//   xh    [3079744 , 9479744)   x as f16 [100000][128]
//   aggd  [9479744 , 15879744)  agg as f16 [100000][128]
// ---------------------------------------------------------------------------
#define WS_LCNT     0
#define WS_TOT      400128
#define WS_BOFFS    401728
#define WS_OFFS     403328
#define WS_SW       503360
#define WS_SW2      1783360
#define WS_WF       3063360
#define WS_XH       3079744
#define WS_AGGD     9479744
#define WS_INTS_TOP 15879744

// MID-tier (R4 fp32 path) layout
#define WS_CNTM     0
#define WS_OFFSM    100000
#define WS_BSUMM    200000
#define WS_SWM      200192
#define WS_WCONV    1480192
#define WS_INTS_MID 1512960

// prepA block partition
#define PREP_XB 3125          // x->f16 : 3125*256*16 = 12.8M elems
#define PREP_WB 128           // W->f16 : 128*256    = 32768 elems
#define PREP_AB EBLK          // passA  : 256 blocks * 2500 edges

typedef __attribute__((ext_vector_type(8))) short    short8v;
typedef __attribute__((ext_vector_type(8))) _Float16 half8v;
typedef __attribute__((ext_vector_type(4))) float    floatx4;
struct __align__(8) half4t { __half2 a, b; };

__device__ inline void split_bf16(float f, short& h, short& l) {
    unsigned u  = __float_as_uint(f);
    unsigned hb = u & 0xFFFF0000u;
    h = (short)(u >> 16);
    float fl = f - __uint_as_float(hb);
    l = (short)(__float_as_uint(fl) >> 16);
}

// ---- fallback path (atomic scatter), used only if ws tiny ------------------
__global__ __launch_bounds__(256) void scatter_kernel(
    const float* __restrict__ x, const int* __restrict__ ei,
    const float* __restrict__ ew, float* agg)
{
    int gid = blockIdx.x * 256 + threadIdx.x;
    int e = gid >> 7, f = gid & 127;
    if (e >= EE) return;
    float v = x[ei[e] * D + f] * ew[e];
    unsafeAtomicAdd(&agg[ei[EE + e] * D + f], v);
}

// ---- prepA: x->f16 | W->f16 | per-block LDS bucket histogram ---------------
__global__ __launch_bounds__(256) void prepA_kernel(
    const float* __restrict__ x, const float* __restrict__ Wrel,
    const float* __restrict__ Wroot, const int* __restrict__ ei,
    short* __restrict__ xh, short* __restrict__ Wf, int* __restrict__ lcnt)
{
    __shared__ int h[BKT];
    const int b = blockIdx.x;
    if (b < PREP_XB) {
        const int base = b * 4096 + threadIdx.x * 4;   // f32 index
        float4 v[4];
        #pragma unroll
        for (int u = 0; u < 4; u++)
            v[u] = *(const float4*)&x[base + u * 1024];
        #pragma unroll
        for (int u = 0; u < 4; u++) {
            short4 hh;
            hh.x = (short)__half_as_ushort(__float2half(v[u].x));
            hh.y = (short)__half_as_ushort(__float2half(v[u].y));
            hh.z = (short)__half_as_ushort(__float2half(v[u].z));
            hh.w = (short)__half_as_ushort(__float2half(v[u].w));
            *(short4*)&xh[base + u * 1024] = hh;
        }
    } else if (b < PREP_XB + PREP_WB) {
        int i = (b - PREP_XB) * 256 + threadIdx.x;   // 0..32767
        int c = i >> 8, k = i & 255;
        float f = (k < 128) ? Wrel[c * 128 + k] : Wroot[c * 128 + (k - 128)];
        Wf[i] = (short)__half_as_ushort(__float2half(f));
    } else {
        const int eb = b - PREP_XB - PREP_WB;        // 0..255
        for (int i = threadIdx.x; i < BKT; i += 256) h[i] = 0;
        __syncthreads();
        const int e0 = eb * EPB, e1 = e0 + EPB;
        for (int e = e0 + threadIdx.x; e < e1; e += 256)
            atomicAdd(&h[ei[EE + e] >> 6], 1);       // LDS atomic (cheap)
        __syncthreads();
        for (int i = threadIdx.x; i < BKT; i += 256)
            lcnt[eb * BKT + i] = h[i];
    }
}

// ---- colscan: per-bucket exclusive scan over 256 block rows (in place) -----
__global__ __launch_bounds__(256) void colscan_kernel(
    int* __restrict__ lcnt, int* __restrict__ tot)
{
    int t = blockIdx.x * 256 + threadIdx.x;
    if (t >= BKT) return;
    int run = 0;
    for (int b = 0; b < EBLK; b++) {
        int v = lcnt[b * BKT + t];
        lcnt[b * BKT + t] = run;     // exclusive prefix
        run += v;
    }
    tot[t] = run;
}

// ---- scanT: exclusive scan of bucket totals -> boffs -----------------------
__global__ __launch_bounds__(256) void scanT_kernel(
    const int* __restrict__ tot, int* __restrict__ boffs)
{
    __shared__ int s[256];
    __shared__ int carry;
    if (threadIdx.x == 0) carry = 0;
    __syncthreads();
    for (int c = 0; c < 7; c++) {                    // 7*256 = 1792 >= 1563
        int idx = c * 256 + threadIdx.x;
        int v = (idx < BKT) ? tot[idx] : 0;
        s[threadIdx.x] = v;
        __syncthreads();
        for (int off = 1; off < 256; off <<= 1) {
            int t = (threadIdx.x >= off) ? s[threadIdx.x - off] : 0;
            __syncthreads();
            s[threadIdx.x] += t;
            __syncthreads();
        }
        if (idx < BKT) boffs[idx] = carry + s[threadIdx.x] - v;
        __syncthreads();
        if (threadIdx.x == 0) carry += s[255];
        __syncthreads();
    }
    if (threadIdx.x == 0) boffs[BKT] = EE;
}

// ---- passB: bucket-grouped scatter (no global atomics) ---------------------
__global__ __launch_bounds__(256) void passB_kernel(
    const int* __restrict__ ei, const float* __restrict__ ew,
    const int* __restrict__ lcnt, const int* __restrict__ boffs,
    int2* __restrict__ sw)
{
    __shared__ int base2[BKT];
    __shared__ int cur[BKT];
    const int eb = blockIdx.x;
    for (int i = threadIdx.x; i < BKT; i += 256) {
        base2[i] = boffs[i] + lcnt[eb * BKT + i];
        cur[i] = 0;
    }
    __syncthreads();
    const int e0 = eb * EPB, e1 = e0 + EPB;
    for (int e = e0 + threadIdx.x; e < e1; e += 256) {
        int src = ei[e];
        int dst = ei[EE + e];
        int bkt = dst >> 6;
        int r = atomicAdd(&cur[bkt], 1);             // LDS rank
        sw[base2[bkt] + r] = make_int2(src | ((dst & 63) << 17),
                                       __float_as_int(ew[e]));
    }
}

// ---- passC: node-exact refine within each bucket + CSR offsets -------------
__global__ __launch_bounds__(256) void passC_kernel(
    const int2* __restrict__ sw, const int* __restrict__ boffs,
    int2* __restrict__ sw2, int* __restrict__ offs)
{
    __shared__ int cnt[64], nb[64], cur[64];
    __shared__ int segbeg, segend;
    const int bkt = blockIdx.x;
    if (threadIdx.x == 0) { segbeg = boffs[bkt]; segend = boffs[bkt + 1]; }
    if (threadIdx.x < 64) { cnt[threadIdx.x] = 0; cur[threadIdx.x] = 0; }
    __syncthreads();
    for (int j = segbeg + threadIdx.x; j < segend; j += 256)
        atomicAdd(&cnt[(sw[j].x >> 17) & 63], 1);
    __syncthreads();
    if (threadIdx.x < 64) nb[threadIdx.x] = cnt[threadIdx.x];
    __syncthreads();
    for (int off = 1; off < 64; off <<= 1) {
        int t = 0;
        if (threadIdx.x < 64 && threadIdx.x >= off) t = nb[threadIdx.x - off];
        __syncthreads();
        if (threadIdx.x < 64) nb[threadIdx.x] += t;
        __syncthreads();
    }
    if (threadIdx.x < 64) {
        int b = segbeg + nb[threadIdx.x] - cnt[threadIdx.x];   // exclusive base
        nb[threadIdx.x] = b;
        int node = bkt * 64 + threadIdx.x;
        if (node < NN) offs[node] = b;
    }
    __syncthreads();
    for (int j = segbeg + threadIdx.x; j < segend; j += 256) {
        int2 v = sw[j];
        int n = (v.x >> 17) & 63;
        int r = atomicAdd(&cur[n], 1);
        sw2[nb[n] + r] = make_int2(v.x & 0x1FFFF, v.y);
    }
    if (bkt == 0 && threadIdx.x == 0) offs[NN] = EE;
}

// ---- aggregate: fp16 gather 4-deep -> dense f16 aggd -----------------------
__global__ __launch_bounds__(256) void aggregate_h_kernel(
    const short* __restrict__ xh, const int* __restrict__ offs,
    const int2* __restrict__ sw2, short* __restrict__ aggd)
{
    const int node = blockIdx.x * 8 + (threadIdx.x >> 5);
    const int fl   = threadIdx.x & 31;
    if (node >= NN) return;
    const int beg = offs[node];
    const int end = offs[node + 1];
    const half4t* xp = (const half4t*)xh;

    float4 a0 = make_float4(0.f, 0.f, 0.f, 0.f);
    float4 a1 = make_float4(0.f, 0.f, 0.f, 0.f);
    int j = beg;
    for (; j + 3 < end; j += 4) {
        int2 s0 = sw2[j], s1 = sw2[j + 1], s2 = sw2[j + 2], s3 = sw2[j + 3];
        half4t v0 = xp[(size_t)s0.x * 32 + fl];
        half4t v1 = xp[(size_t)s1.x * 32 + fl];
        half4t v2 = xp[(size_t)s2.x * 32 + fl];
        half4t v3 = xp[(size_t)s3.x * 32 + fl];
        float w0 = __int_as_float(s0.y), w1 = __int_as_float(s1.y);
        float w2 = __int_as_float(s2.y), w3 = __int_as_float(s3.y);
        float2 l0 = __half22float2(v0.a), h0 = __half22float2(v0.b);
        float2 l1 = __half22float2(v1.a), h1 = __half22float2(v1.b);
        float2 l2 = __half22float2(v2.a), h2 = __half22float2(v2.b);
        float2 l3 = __half22float2(v3.a), h3 = __half22float2(v3.b);
        a0.x += w0 * l0.x; a0.y += w0 * l0.y; a0.z += w0 * h0.x; a0.w += w0 * h0.y;
        a1.x += w1 * l1.x; a1.y += w1 * l1.y; a1.z += w1 * h1.x; a1.w += w1 * h1.y;
        a0.x += w2 * l2.x; a0.y += w2 * l2.y; a0.z += w2 * h2.x; a0.w += w2 * h2.y;
        a1.x += w3 * l3.x; a1.y += w3 * l3.y; a1.z += w3 * h3.x; a1.w += w3 * h3.y;
    }
    for (; j + 1 < end; j += 2) {
        int2 s0 = sw2[j], s1 = sw2[j + 1];
        half4t v0 = xp[(size_t)s0.x * 32 + fl];
        half4t v1 = xp[(size_t)s1.x * 32 + fl];
        float w0 = __int_as_float(s0.y), w1 = __int_as_float(s1.y);
        float2 l0 = __half22float2(v0.a), h0 = __half22float2(v0.b);
        float2 l1 = __half22float2(v1.a), h1 = __half22float2(v1.b);
        a0.x += w0 * l0.x; a0.y += w0 * l0.y; a0.z += w0 * h0.x; a0.w += w0 * h0.y;
        a1.x += w1 * l1.x; a1.y += w1 * l1.y; a1.z += w1 * h1.x; a1.w += w1 * h1.y;
    }
    if (j < end) {
        int2 s0 = sw2[j];
        half4t v0 = xp[(size_t)s0.x * 32 + fl];
        float w0 = __int_as_float(s0.y);
        float2 l0 = __half22float2(v0.a), h0 = __half22float2(v0.b);
        a0.x += w0 * l0.x; a0.y += w0 * l0.y; a0.z += w0 * h0.x; a0.w += w0 * h0.y;
    }
    float4 r = make_float4(a0.x + a1.x, a0.y + a1.y, a0.z + a1.z, a0.w + a1.w);
    half4t o;
    o.a = __floats2half2_rn(r.x, r.y);
    o.b = __floats2half2_rn(r.z, r.w);
    ((half4t*)aggd)[(size_t)node * 32 + fl] = o;
}

// ---- f16 MFMA GEMM: out = [aggd|xh] @ Wf^T + b -----------------------------
__global__ __launch_bounds__(256) void mfma_f16_kernel(
    const short* __restrict__ xh, const short* __restrict__ aggd,
    const short* __restrict__ Wf, const float* __restrict__ bias,
    float* __restrict__ out)
{
    __shared__ short lds[2 * 128 * 64];   // At, Wt : 32 KB
    short* At = lds;
    short* Wt = lds + 8192;

    const int tid  = threadIdx.x;
    const int lane = tid & 63;
    const int wave = tid >> 6;
    const int row0 = blockIdx.x * 128;
    const int frow = lane & 15;

    floatx4 acc[2][8];
    #pragma unroll
    for (int nf = 0; nf < 8; nf++) {
        float b = bias[nf * 16 + frow];
        #pragma unroll
        for (int mf = 0; mf < 2; mf++) acc[mf][nf] = (floatx4){b, b, b, b};
    }

    for (int kc = 0; kc < 4; kc++) {
        const short* A = (kc < 2) ? aggd : xh;       // both [NN][128] f16
        const int kcol = (kc & 1) * 64;
        __syncthreads();
        #pragma unroll
        for (int i = 0; i < 4; i++) {
            int e = (i * 256 + tid) * 8;
            int r = e >> 6, k = e & 63;
            int rg = row0 + r;
            short8v v = (short8v)0;
            if (rg < NN) v = *(const short8v*)&A[(size_t)rg * 128 + kcol + k];
            int sidx = r * 64 + (((k >> 3) ^ (r & 7)) << 3);
            *(short8v*)&At[sidx] = v;
        }
        #pragma unroll
        for (int i = 0; i < 4; i++) {
            int e = (i * 256 + tid) * 8;
            int c = e >> 6, k = e & 63;
            int sidx = c * 64 + (((k >> 3) ^ (c & 7)) << 3);
            *(short8v*)&Wt[sidx] = *(const short8v*)&Wf[c * 256 + kc * 64 + k];
        }
        __syncthreads();

        const int arow = wave * 32;
        #pragma unroll
        for (int kf = 0; kf < 2; kf++) {
            const int kblk = kf * 4 + (lane >> 4);
            half8v a[2];
            #pragma unroll
            for (int mf = 0; mf < 2; mf++) {
                int r = arow + mf * 16 + frow;
                int idx = r * 64 + ((kblk ^ (r & 7)) << 3);
                a[mf] = *(const half8v*)&At[idx];
            }
            #pragma unroll
            for (int nf = 0; nf < 8; nf++) {
                int cc = nf * 16 + frow;
                int idx = cc * 64 + ((kblk ^ (cc & 7)) << 3);
                half8v b = *(const half8v*)&Wt[idx];
                #pragma unroll
                for (int mf = 0; mf < 2; mf++)
                    acc[mf][nf] = __builtin_amdgcn_mfma_f32_16x16x32_f16(a[mf], b, acc[mf][nf], 0, 0, 0);
            }
        }
    }

    const int orow = row0 + wave * 32;
    #pragma unroll
    for (int mf = 0; mf < 2; mf++) {
        #pragma unroll
        for (int j = 0; j < 4; j++) {
            int r = orow + mf * 16 + (lane >> 4) * 4 + j;
            if (r < NN) {
                #pragma unroll
                for (int nf = 0; nf < 8; nf++)
                    out[(size_t)r * D + nf * 16 + (lane & 15)] = acc[mf][nf][j];
            }
        }
    }
}

// ======================= MID-tier kernels (R4 fp32 path) =====================
__global__ __launch_bounds__(256) void zero_cnt_kernel(int* __restrict__ cnt)
{
    int i = blockIdx.x * 256 + threadIdx.x;
    if (i < NBINS) cnt[i] = 0;
}

__global__ __launch_bounds__(256) void hist_kernel(
    const int* __restrict__ ei, int* __restrict__ cnt)
{
    int e = blockIdx.x * 256 + threadIdx.x;
    if (e < EE) atomicAdd(&cnt[ei[EE + e]], 1);
}

__global__ __launch_bounds__(256) void wconv_kernel(
    const float* __restrict__ Wrel, const float* __restrict__ Wroot,
    short* __restrict__ Wb)
{
    int i = blockIdx.x * 256 + threadIdx.x;
    int c = i >> 8, k = i & 255;
    float f = (k < 128) ? Wrel[c * 128 + k] : Wroot[c * 128 + (k - 128)];
    short h, l;
    split_bf16(f, h, l);
    Wb[i] = h;
    Wb[32768 + i] = l;
}

__global__ __launch_bounds__(256) void scanA_kernel(
    const int* __restrict__ cnt, int* __restrict__ offs, int* __restrict__ bsum)
{
    __shared__ int tsum[256];
    const int tid = threadIdx.x;
    const int base = blockIdx.x * 1024 + tid * 4;
    int v[4], s = 0;
    #pragma unroll
    for (int i = 0; i < 4; i++) {
        int idx = base + i;
        v[i] = (idx < NBINS) ? cnt[idx] : 0;
        s += v[i];
    }
    tsum[tid] = s;
    __syncthreads();
    for (int off = 1; off < 256; off <<= 1) {
        int t = (tid >= off) ? tsum[tid - off] : 0;
        __syncthreads();
        tsum[tid] += t;
        __syncthreads();
    }
    int run = tsum[tid] - s;
    #pragma unroll
    for (int i = 0; i < 4; i++) {
        int idx = base + i;
        if (idx < NBINS) offs[idx] = run;
        run += v[i];
    }
    if (tid == 255) bsum[blockIdx.x] = tsum[255];
}

__global__ __launch_bounds__(256) void scanC_kernel(
    int* __restrict__ offs, const int* __restrict__ bsum)
{
    __shared__ int s[128];
    const int tid = threadIdx.x;
    if (tid < 128) s[tid] = (tid < SCAN_NBLK) ? bsum[tid] : 0;
    __syncthreads();
    for (int off = 1; off < 128; off <<= 1) {
        int t = 0;
        if (tid < 128 && tid >= off) t = s[tid - off];
        __syncthreads();
        if (tid < 128) s[tid] += t;
        __syncthreads();
    }
    const int add = (blockIdx.x == 0) ? 0 : s[blockIdx.x - 1];
    const int base = blockIdx.x * 1024 + tid * 4;
    #pragma unroll
    for (int i = 0; i < 4; i++) {
        int idx = base + i;
        if (idx < NBINS) offs[idx] += add;
    }
}

__global__ __launch_bounds__(256) void buildM_kernel(
    const int* __restrict__ ei, const float* __restrict__ ew,
    int* __restrict__ offs, int2* __restrict__ sw)
{
    int e = blockIdx.x * 256 + threadIdx.x;
    if (e >= EE) return;
    int dst = ei[EE + e];
    int p = atomicAdd(&offs[dst], 1);
    sw[p] = make_int2(ei[e], __float_as_int(ew[e]));
}

__global__ __launch_bounds__(256) void aggregate_kernel(
    const float* __restrict__ x, const int* __restrict__ offs,
    const int2* __restrict__ sw, float* __restrict__ out)
{
    const int node = blockIdx.x * 8 + (threadIdx.x >> 5);
    const int fl   = threadIdx.x & 31;
    if (node >= NN) return;
    const int beg = (node == 0) ? 0 : offs[node - 1];
    const int end = offs[node];
    const float4* x4 = (const float4*)x;

    float4 a0 = make_float4(0.f, 0.f, 0.f, 0.f);
    float4 a1 = make_float4(0.f, 0.f, 0.f, 0.f);
    int j = beg;
    for (; j + 1 < end; j += 2) {
        int2 s0 = sw[j];
        int2 s1 = sw[j + 1];
        float4 v0 = x4[(size_t)s0.x * 32 + fl];
        float4 v1 = x4[(size_t)s1.x * 32 + fl];
        float w0 = __int_as_float(s0.y), w1 = __int_as_float(s1.y);
        a0.x += w0 * v0.x; a0.y += w0 * v0.y; a0.z += w0 * v0.z; a0.w += w0 * v0.w;
        a1.x += w1 * v1.x; a1.y += w1 * v1.y; a1.z += w1 * v1.z; a1.w += w1 * v1.w;
    }
    if (j < end) {
        int2 s0 = sw[j];
        float4 v0 = x4[(size_t)s0.x * 32 + fl];
        float w0 = __int_as_float(s0.y);
        a0.x += w0 * v0.x; a0.y += w0 * v0.y; a0.z += w0 * v0.z; a0.w += w0 * v0.w;
    }
    float4 r = make_float4(a0.x + a1.x, a0.y + a1.y, a0.z + a1.z, a0.w + a1.w);
    ((float4*)out)[(size_t)node * 32 + fl] = r;
}

__global__ __launch_bounds__(256) void mfma_gemm_kernel(
    const float* __restrict__ x, const short* __restrict__ Wb,
    const float* __restrict__ bias, float* __restrict__ out)
{
    __shared__ short lds[4 * 128 * 64];
    short* Ah = lds;
    short* Al = lds + 8192;
    short* Wh = lds + 16384;
    short* Wl = lds + 24576;

    const int tid  = threadIdx.x;
    const int lane = tid & 63;
    const int wave = tid >> 6;
    const int row0 = blockIdx.x * 128;
    const int frow = lane & 15;
    const int fk   = (lane >> 4) * 8;

    floatx4 acc[2][8];
    #pragma unroll
    for (int nf = 0; nf < 8; nf++) {
        float b = bias[nf * 16 + frow];
        #pragma unroll
        for (int mf = 0; mf < 2; mf++) acc[mf][nf] = (floatx4){b, b, b, b};
    }

    for (int kc = 0; kc < 4; kc++) {
        const float* A = (kc < 2) ? out : x;
        const int kcol = (kc & 1) * 64;
        __syncthreads();
        #pragma unroll
        for (int i = 0; i < 8; i++) {
            int e = (i * 256 + tid) * 4;
            int r = e >> 6, k = e & 63;
            int rg = row0 + r;
            float4 v = (rg < NN) ? *(const float4*)&A[(size_t)rg * D + kcol + k]
                                 : make_float4(0.f, 0.f, 0.f, 0.f);
            short4 h, l;
            split_bf16(v.x, h.x, l.x);
            split_bf16(v.y, h.y, l.y);
            split_bf16(v.z, h.z, l.z);
            split_bf16(v.w, h.w, l.w);
            int sidx = r * 64 + (((k >> 3) ^ (r & 7)) << 3) + (k & 7);
            *(short4*)&Ah[sidx] = h;
            *(short4*)&Al[sidx] = l;
        }
        #pragma unroll
        for (int i = 0; i < 4; i++) {
            int e = (i * 256 + tid) * 8;
            int c = e >> 6, k = e & 63;
            int sidx = c * 64 + (((k >> 3) ^ (c & 7)) << 3);
            int g = c * 256 + kc * 64 + k;
            *(short8v*)&Wh[sidx] = *(const short8v*)&Wb[g];
            *(short8v*)&Wl[sidx] = *(const short8v*)&Wb[32768 + g];
        }
        __syncthreads();

        const int arow = wave * 32;
        #pragma unroll
        for (int kf = 0; kf < 2; kf++) {
            const int kblk = (kf * 32 + fk) >> 3;
            short8v ah[2], al[2];
            #pragma unroll
            for (int mf = 0; mf < 2; mf++) {
                int r = arow + mf * 16 + frow;
                int idx = r * 64 + ((kblk ^ (r & 7)) << 3);
                ah[mf] = *(const short8v*)&Ah[idx];
                al[mf] = *(const short8v*)&Al[idx];
            }
            #pragma unroll
            for (int nf = 0; nf < 8; nf++) {
                int cc = nf * 16 + frow;
                int idx = cc * 64 + ((kblk ^ (cc & 7)) << 3);
                short8v bh = *(const short8v*)&Wh[idx];
                short8v bl = *(const short8v*)&Wl[idx];
                #pragma unroll
                for (int mf = 0; mf < 2; mf++) {
                    acc[mf][nf] = __builtin_amdgcn_mfma_f32_16x16x32_bf16(ah[mf], bh, acc[mf][nf], 0, 0, 0);
                    acc[mf][nf] = __builtin_amdgcn_mfma_f32_16x16x32_bf16(al[mf], bh, acc[mf][nf], 0, 0, 0);
                    acc[mf][nf] = __builtin_amdgcn_mfma_f32_16x16x32_bf16(ah[mf], bl, acc[mf][nf], 0, 0, 0);
                }
            }
        }
    }

    const int orow = row0 + wave * 32;
    #pragma unroll
    for (int mf = 0; mf < 2; mf++) {
        #pragma unroll
        for (int j = 0; j < 4; j++) {
            int r = orow + mf * 16 + (lane >> 4) * 4 + j;
            if (r < NN) {
                #pragma unroll
                for (int nf = 0; nf < 8; nf++)
                    out[(size_t)r * D + nf * 16 + (lane & 15)] = acc[mf][nf][j];
            }
        }
    }
}

// ---- fallback fp32 GEMM (atomic tier only) ---------------------------------
__global__ __launch_bounds__(512) void gemm_kernel(
    const float* __restrict__ x, const float* __restrict__ Wrel,
    const float* __restrict__ Wroot, const float* __restrict__ bias,
    float* out)
{
    __shared__ float AtT[128][65];
    const int tid  = threadIdx.x;
    const int lane = tid & 63;
    const int wid  = __builtin_amdgcn_readfirstlane(tid >> 6);
    const int row0 = blockIdx.x * 64;
    float acc[16];
    {
        const float* bb = bias + wid * 16;
        #pragma unroll
        for (int c = 0; c < 16; c++) acc[c] = bb[c];
    }
    for (int phase = 0; phase < 2; phase++) {
        const float* A = phase ? x : out;
        const float* W = (phase ? Wroot : Wrel) + wid * 16 * D;
        __syncthreads();
        #pragma unroll
        for (int i = 0; i < 16; i++) {
            int e = i * 512 + tid;
            int r = e >> 7, k = e & 127;
            int rg = row0 + r;
            AtT[k][r] = (rg < NN) ? A[rg * D + k] : 0.0f;
        }
        __syncthreads();
        for (int k4 = 0; k4 < 32; k4++) {
            float a0 = AtT[k4 * 4 + 0][lane];
            float a1 = AtT[k4 * 4 + 1][lane];
            float a2 = AtT[k4 * 4 + 2][lane];
            float a3 = AtT[k4 * 4 + 3][lane];
            #pragma unroll
            for (int c = 0; c < 16; c++) {
                const float* wp = W + c * D + k4 * 4;
                acc[c] += a0 * wp[0] + a1 * wp[1] + a2 * wp[2] + a3 * wp[3];
            }
        }
    }
    __syncthreads();
    #pragma unroll
    for (int c = 0; c < 16; c++)
        AtT[wid * 16 + c][lane] = acc[c];
    __syncthreads();
    #pragma unroll
    for (int i = 0; i < 16; i++) {
        int e = i * 512 + tid;
        int r = e >> 7, col = e & 127;
        int rg = row0 + r;
        if (rg < NN) out[rg * D + col] = AtT[col][r];
    }
}

extern "C" void kernel_launch(void* const* d_in, const int* in_sizes, int n_in,
                              void* d_out, int out_size, void* d_ws, size_t ws_size,
                              hipStream_t stream) {
    const float* x     = (const float*)d_in[0];
    const int*   ei    = (const int*)  d_in[1];
    const float* ew    = (const float*)d_in[2];
    const float* Wrel  = (const float*)d_in[3];
    const float* Wroot = (const float*)d_in[4];
    const float* bias  = (const float*)d_in[5];
    float*       out   = (float*)d_out;

    const int eb = (EE + 255) / 256;

    if (ws_size >= (size_t)WS_INTS_TOP * sizeof(int)) {
        int* w = (int*)d_ws;
        int*   lcnt  = w + WS_LCNT;
        int*   tot   = w + WS_TOT;
        int*   boffs = w + WS_BOFFS;
        int*   offs  = w + WS_OFFS;
        int2*  sw    = (int2*)(w + WS_SW);
        int2*  sw2   = (int2*)(w + WS_SW2);
        short* Wf    = (short*)(w + WS_WF);
        short* xh    = (short*)(w + WS_XH);
        short* aggd  = (short*)(w + WS_AGGD);

        prepA_kernel<<<PREP_XB + PREP_WB + PREP_AB, 256, 0, stream>>>(
            x, Wrel, Wroot, ei, xh, Wf, lcnt);
        colscan_kernel<<<(BKT + 255) / 256, 256, 0, stream>>>(lcnt, tot);
        scanT_kernel<<<1, 256, 0, stream>>>(tot, boffs);
        passB_kernel<<<EBLK, 256, 0, stream>>>(ei, ew, lcnt, boffs, sw);
        passC_kernel<<<BKT, 256, 0, stream>>>(sw, boffs, sw2, offs);
        aggregate_h_kernel<<<NN / 8, 256, 0, stream>>>(xh, offs, sw2, aggd);
        mfma_f16_kernel<<<(NN + 127) / 128, 256, 0, stream>>>(xh, aggd, Wf, bias, out);
    } else if (ws_size >= (size_t)WS_INTS_MID * sizeof(int)) {
        int* w = (int*)d_ws;
        int*   cnt  = w + WS_CNTM;
        int*   offs = w + WS_OFFSM;
        int*   bsum = w + WS_BSUMM;
        int2*  sw   = (int2*)(w + WS_SWM);
        short* Wb   = (short*)(w + WS_WCONV);

        zero_cnt_kernel<<<(NBINS + 255) / 256, 256, 0, stream>>>(cnt);
        wconv_kernel<<<128, 256, 0, stream>>>(Wrel, Wroot, Wb);
        hist_kernel <<<eb, 256, 0, stream>>>(ei, cnt);
        scanA_kernel<<<SCAN_NBLK, 256, 0, stream>>>(cnt, offs, bsum);
        scanC_kernel<<<SCAN_NBLK, 256, 0, stream>>>(offs, bsum);
        buildM_kernel<<<eb, 256, 0, stream>>>(ei, ew, offs, sw);
        aggregate_kernel<<<NN / 8, 256, 0, stream>>>(x, offs, sw, out);
        mfma_gemm_kernel<<<(NN + 127) / 128, 256, 0, stream>>>(x, Wb, bias, out);
    } else {
        hipMemsetAsync(out, 0, (size_t)NN * D * sizeof(float), stream);
        scatter_kernel<<<(EE * 128) / 256, 256, 0, stream>>>(x, ei, ew, out);
        gemm_kernel<<<(NN + 63) / 64, 512, 0, stream>>>(x, Wrel, Wroot, bias, out);
    }
}